// Round 1
// baseline (114.352 us; speedup 1.0000x reference)
//
#include <hip/hip_runtime.h>
#include <stdint.h>

#define HIDDEN 512
#define NDRUG 2000
#define NREACT 10000
#define NEDGE 400000

typedef __attribute__((ext_vector_type(8))) __bf16 bf16x8;
typedef __attribute__((ext_vector_type(4))) float f32x4;
typedef __attribute__((ext_vector_type(8))) unsigned short ushort8;
typedef __attribute__((ext_vector_type(4))) unsigned short ushort4v;
typedef __attribute__((ext_vector_type(4))) float float4v;

__device__ __forceinline__ unsigned short f2bf(float f) {
  union { float f; unsigned int u; } v; v.f = f;
  unsigned int u = v.u;
  unsigned int r = (u + 0x7fffu + ((u >> 16) & 1u)) >> 16;  // RNE
  return (unsigned short)r;
}
__device__ __forceinline__ float bf2f(unsigned short h) {
  union { unsigned int u; float f; } v; v.u = ((unsigned int)h) << 16;
  return v.f;
}

// ---------------- cast f32 -> bf16 (n in float4-quads) ----------------
__global__ __launch_bounds__(256) void cast_kernel(const float* __restrict__ in,
                                                   unsigned short* __restrict__ out,
                                                   int nquads) {
  int i = blockIdx.x * blockDim.x + threadIdx.x;
  int stride = gridDim.x * blockDim.x;
  for (; i < nquads; i += stride) {
    float4v v = *reinterpret_cast<const float4v*>(in + (size_t)i * 4);
    ushort4v q;
    q[0] = f2bf(v[0]); q[1] = f2bf(v[1]); q[2] = f2bf(v[2]); q[3] = f2bf(v[3]);
    *reinterpret_cast<ushort4v*>(out + (size_t)i * 4) = q;
  }
}

// ---------------- split W1 (512 x 1024) into left/right bf16 halves ----------------
__global__ __launch_bounds__(256) void splitw1(const float* __restrict__ W1,
                                               unsigned short* __restrict__ WL,
                                               unsigned short* __restrict__ WR) {
  const int NQ = HIDDEN * 2 * HIDDEN / 4;  // 131072 quads
  int i = blockIdx.x * blockDim.x + threadIdx.x;
  int stride = gridDim.x * blockDim.x;
  for (; i < NQ; i += stride) {
    int e = i * 4;
    int o = e >> 10;         // output row (0..511)
    int j = e & 1023;        // input col
    float4v v = *reinterpret_cast<const float4v*>(W1 + e);
    ushort4v q;
    q[0] = f2bf(v[0]); q[1] = f2bf(v[1]); q[2] = f2bf(v[2]); q[3] = f2bf(v[3]);
    if (j < HIDDEN)
      *reinterpret_cast<ushort4v*>(WL + o * HIDDEN + j) = q;
    else
      *reinterpret_cast<ushort4v*>(WR + o * HIDDEN + (j - HIDDEN)) = q;
  }
}

// ---------------- bf16 MFMA GEMM, C[m][n] = sum_k A[m][k]*B[n][k] (+bias[n]) ----------------
// m97-style: 128x128 tile, BK=32, global_load_lds dwordx4 staging, 4 waves (2x2) x 64x64.
#define BM 128
#define BN 128
#define BK 32

__global__ __launch_bounds__(256) void gemm_bt(
    const unsigned short* __restrict__ Adrug,   // 2000 x 512 bf16
    const unsigned short* __restrict__ Areac,   // 10000 x 512 bf16
    const unsigned short* __restrict__ BL,      // 512 x 512 bf16 (o-major, k contiguous)
    const unsigned short* __restrict__ BR,      // 512 x 512 bf16
    const float* __restrict__ bias,             // b1 (folded into drug panel only)
    unsigned short* __restrict__ Hd,            // 2000 x 512 bf16 out
    unsigned short* __restrict__ Hr)            // 10000 x 512 bf16 out
{
  const int z = blockIdx.z;
  const int mb = blockIdx.x;
  const int nb = blockIdx.y;
  const int M = (z == 0) ? NDRUG : NREACT;
  if (mb * BM >= M) return;
  const unsigned short* A = (z == 0) ? Adrug : Areac;
  const unsigned short* B = (z == 0) ? BL : BR;
  unsigned short* C = (z == 0) ? Hd : Hr;
  const bool has_bias = (z == 0);
  const int K = HIDDEN, N = HIDDEN;

  __shared__ __bf16 As[BM * BK];
  __shared__ __bf16 Bs[BN * BK];

  const int tid = threadIdx.x;
  const int lane = tid & 63;
  const int wid = tid >> 6;       // 0..3
  const int wm = wid >> 1;        // wave row in 2x2
  const int wn = wid & 1;         // wave col

  f32x4 acc[4][4];
#pragma unroll
  for (int i = 0; i < 4; ++i)
#pragma unroll
    for (int j = 0; j < 4; ++j) acc[i][j] = (f32x4){0.f, 0.f, 0.f, 0.f};

  const int row0 = mb * BM;
  const int col0 = nb * BN;
  const int srow = lane >> 2;           // 0..15 (row within 16-row stripe)
  const int scol = (lane & 3) * 8;      // bf16 col within 32-wide row

  for (int kt = 0; kt < K; kt += BK) {
    // stage A (128x32) and B (128x32): each wave 2 calls each, 1KB per call
#pragma unroll
    for (int i = 0; i < 2; ++i) {
      int rA = row0 + wid * 32 + i * 16 + srow;
      rA = rA < M ? rA : M - 1;                      // clamp for ragged M
      const unsigned short* gA = A + (size_t)rA * K + kt + scol;
      __bf16* lA = As + (wid * 32 + i * 16) * BK;    // wave-uniform base; HW adds lane*16B
      __builtin_amdgcn_global_load_lds(
          (const __attribute__((address_space(1))) void*)gA,
          (__attribute__((address_space(3))) void*)lA, 16, 0, 0);
      int rB = col0 + wid * 32 + i * 16 + srow;      // N=512, exact
      const unsigned short* gB = B + (size_t)rB * K + kt + scol;
      __bf16* lB = Bs + (wid * 32 + i * 16) * BK;
      __builtin_amdgcn_global_load_lds(
          (const __attribute__((address_space(1))) void*)gB,
          (__attribute__((address_space(3))) void*)lB, 16, 0, 0);
    }
    __syncthreads();

    const int fr = lane & 15;
    const int kg = (lane >> 4) * 8;
    bf16x8 af[4], bfr[4];
#pragma unroll
    for (int mi = 0; mi < 4; ++mi)
      af[mi] = *reinterpret_cast<const bf16x8*>(As + (wm * 64 + mi * 16 + fr) * BK + kg);
#pragma unroll
    for (int ni = 0; ni < 4; ++ni)
      bfr[ni] = *reinterpret_cast<const bf16x8*>(Bs + (wn * 64 + ni * 16 + fr) * BK + kg);
#pragma unroll
    for (int mi = 0; mi < 4; ++mi)
#pragma unroll
      for (int ni = 0; ni < 4; ++ni)
        acc[mi][ni] = __builtin_amdgcn_mfma_f32_16x16x32_bf16(af[mi], bfr[ni], acc[mi][ni], 0, 0, 0);
    __syncthreads();
  }

  // epilogue: C/D layout col=lane&15, row=(lane>>4)*4+j   [verified m89/m91]
  const int crow = (lane >> 4) * 4;
  const int ccol = lane & 15;
#pragma unroll
  for (int ni = 0; ni < 4; ++ni) {
    const int gc = col0 + wn * 64 + ni * 16 + ccol;
    const float bv = has_bias ? bias[gc] : 0.0f;
#pragma unroll
    for (int mi = 0; mi < 4; ++mi) {
#pragma unroll
      for (int j = 0; j < 4; ++j) {
        const int gr = row0 + wm * 64 + mi * 16 + crow + j;
        if (gr < M) C[(size_t)gr * N + gc] = f2bf(acc[mi][ni][j] + bv);
      }
    }
  }
}

// ---------------- edge kernel: out[e] = W2 . relu(Hd[row[e]] + Hr[col[e]]) + b2 ----------------
__global__ __launch_bounds__(256) void edge_kernel(
    const unsigned short* __restrict__ Hd,
    const unsigned short* __restrict__ Hr,
    const int* __restrict__ row,
    const int* __restrict__ col,
    const float* __restrict__ W2,
    const float* __restrict__ b2,
    float* __restrict__ out)
{
  const int lane = threadIdx.x & 63;
  const int wave = (blockIdx.x * blockDim.x + threadIdx.x) >> 6;
  const int nwaves = (gridDim.x * blockDim.x) >> 6;

  // W2 fragment: lane holds elems [lane*8, lane*8+8)
  float w2v[8];
  *reinterpret_cast<float4v*>(w2v)     = *reinterpret_cast<const float4v*>(W2 + lane * 8);
  *reinterpret_cast<float4v*>(w2v + 4) = *reinterpret_cast<const float4v*>(W2 + lane * 8 + 4);
  const float bias2 = *b2;

  for (int e = wave; e < NEDGE; e += nwaves) {
    const int r = row[e];
    const int c = col[e];
    ushort8 hd = *reinterpret_cast<const ushort8*>(Hd + (size_t)r * HIDDEN + lane * 8);
    ushort8 hr = *reinterpret_cast<const ushort8*>(Hr + (size_t)c * HIDDEN + lane * 8);
    float acc = 0.f;
#pragma unroll
    for (int j = 0; j < 8; ++j) {
      float v = bf2f(hd[j]) + bf2f(hr[j]);
      v = v > 0.f ? v : 0.f;
      acc += w2v[j] * v;
    }
#pragma unroll
    for (int off = 32; off >= 1; off >>= 1)
      acc += __shfl_xor(acc, off);
    if (lane == 0) out[e] = acc + bias2;
  }
}

extern "C" void kernel_launch(void* const* d_in, const int* in_sizes, int n_in,
                              void* d_out, int out_size, void* d_ws, size_t ws_size,
                              hipStream_t stream) {
  const float* z_drug  = (const float*)d_in[0];
  const float* z_react = (const float*)d_in[1];
  const int*   row     = (const int*)d_in[2];
  const int*   col     = (const int*)d_in[3];
  const float* W1      = (const float*)d_in[4];
  const float* b1      = (const float*)d_in[5];
  const float* W2      = (const float*)d_in[6];
  const float* b2      = (const float*)d_in[7];
  float* out = (float*)d_out;

  char* ws = (char*)d_ws;
  size_t off = 0;
  auto alloc = [&](size_t bytes) {
    void* p = ws + off;
    off += (bytes + 255) & ~(size_t)255;
    return p;
  };
  unsigned short* zd_bf = (unsigned short*)alloc((size_t)NDRUG * HIDDEN * 2);
  unsigned short* zr_bf = (unsigned short*)alloc((size_t)NREACT * HIDDEN * 2);
  unsigned short* wl_bf = (unsigned short*)alloc((size_t)HIDDEN * HIDDEN * 2);
  unsigned short* wr_bf = (unsigned short*)alloc((size_t)HIDDEN * HIDDEN * 2);
  unsigned short* Hd    = (unsigned short*)alloc((size_t)NDRUG * HIDDEN * 2);
  unsigned short* Hr    = (unsigned short*)alloc((size_t)NREACT * HIDDEN * 2);

  cast_kernel<<<512, 256, 0, stream>>>(z_drug, zd_bf, NDRUG * HIDDEN / 4);
  cast_kernel<<<2048, 256, 0, stream>>>(z_react, zr_bf, NREACT * HIDDEN / 4);
  splitw1<<<512, 256, 0, stream>>>(W1, wl_bf, wr_bf);

  dim3 ggrid((NREACT + BM - 1) / BM, HIDDEN / BN, 2);  // (79, 4, 2)
  gemm_bt<<<ggrid, 256, 0, stream>>>(zd_bf, zr_bf, wl_bf, wr_bf, b1, Hd, Hr);

  edge_kernel<<<2048, 256, 0, stream>>>(Hd, Hr, row, col, W2, b2, out);
}

// Round 2
// 105.991 us; speedup vs baseline: 1.0789x; 1.0789x over previous
//
#include <hip/hip_runtime.h>
#include <stdint.h>

#define HIDDEN 512
#define NDRUG 2000
#define NREACT 10000
#define NEDGE 400000

typedef __attribute__((ext_vector_type(8))) _Float16 f16x8;
typedef __attribute__((ext_vector_type(2))) _Float16 f16x2;
typedef __attribute__((ext_vector_type(4))) float f32x4;
typedef __attribute__((ext_vector_type(4))) float float4v;
typedef __attribute__((ext_vector_type(4))) _Float16 f16x4;

#if defined(__has_builtin)
#if __has_builtin(__builtin_amdgcn_fdot2)
#define HAVE_FDOT2 1
#endif
#endif

// ---------------- cast f32 -> f16 (n in float4-quads) ----------------
__global__ __launch_bounds__(256) void cast_kernel(const float* __restrict__ in,
                                                   _Float16* __restrict__ out,
                                                   int nquads) {
  int i = blockIdx.x * blockDim.x + threadIdx.x;
  int stride = gridDim.x * blockDim.x;
  for (; i < nquads; i += stride) {
    float4v v = *reinterpret_cast<const float4v*>(in + (size_t)i * 4);
    f16x4 q;
    q[0] = (_Float16)v[0]; q[1] = (_Float16)v[1];
    q[2] = (_Float16)v[2]; q[3] = (_Float16)v[3];
    *reinterpret_cast<f16x4*>(out + (size_t)i * 4) = q;
  }
}

// ---------------- split W1 (512 x 1024) into left/right f16 halves ----------------
__global__ __launch_bounds__(256) void splitw1(const float* __restrict__ W1,
                                               _Float16* __restrict__ WL,
                                               _Float16* __restrict__ WR) {
  const int NQ = HIDDEN * 2 * HIDDEN / 4;  // 131072 quads
  int i = blockIdx.x * blockDim.x + threadIdx.x;
  int stride = gridDim.x * blockDim.x;
  for (; i < NQ; i += stride) {
    int e = i * 4;
    int o = e >> 10;         // output row (0..511)
    int j = e & 1023;        // input col
    float4v v = *reinterpret_cast<const float4v*>(W1 + e);
    f16x4 q;
    q[0] = (_Float16)v[0]; q[1] = (_Float16)v[1];
    q[2] = (_Float16)v[2]; q[3] = (_Float16)v[3];
    if (j < HIDDEN)
      *reinterpret_cast<f16x4*>(WL + o * HIDDEN + j) = q;
    else
      *reinterpret_cast<f16x4*>(WR + o * HIDDEN + (j - HIDDEN)) = q;
  }
}

// ---------------- f16 MFMA GEMM, C[m][n] = sum_k A[m][k]*B[n][k] (+bias[n]) ----------------
#define BM 128
#define BN 128
#define BK 32

__global__ __launch_bounds__(256) void gemm_bt(
    const _Float16* __restrict__ Adrug,   // 2000 x 512 f16
    const _Float16* __restrict__ Areac,   // 10000 x 512 f16
    const _Float16* __restrict__ BL,      // 512 x 512 f16 (o-major, k contiguous)
    const _Float16* __restrict__ BR,      // 512 x 512 f16
    const float* __restrict__ bias,       // b1 (folded into drug panel only)
    _Float16* __restrict__ Hd,            // 2000 x 512 f16 out
    _Float16* __restrict__ Hr)            // 10000 x 512 f16 out
{
  const int z = blockIdx.z;
  const int mb = blockIdx.x;
  const int nb = blockIdx.y;
  const int M = (z == 0) ? NDRUG : NREACT;
  if (mb * BM >= M) return;
  const _Float16* A = (z == 0) ? Adrug : Areac;
  const _Float16* B = (z == 0) ? BL : BR;
  _Float16* C = (z == 0) ? Hd : Hr;
  const bool has_bias = (z == 0);
  const int K = HIDDEN, N = HIDDEN;

  __shared__ _Float16 As[BM * BK];
  __shared__ _Float16 Bs[BN * BK];

  const int tid = threadIdx.x;
  const int lane = tid & 63;
  const int wid = tid >> 6;       // 0..3
  const int wm = wid >> 1;        // wave row in 2x2
  const int wn = wid & 1;         // wave col

  f32x4 acc[4][4];
#pragma unroll
  for (int i = 0; i < 4; ++i)
#pragma unroll
    for (int j = 0; j < 4; ++j) acc[i][j] = (f32x4){0.f, 0.f, 0.f, 0.f};

  const int row0 = mb * BM;
  const int col0 = nb * BN;
  const int srow = lane >> 2;           // 0..15 (row within 16-row stripe)
  const int scol = (lane & 3) * 8;      // f16 col within 32-wide row

  for (int kt = 0; kt < K; kt += BK) {
#pragma unroll
    for (int i = 0; i < 2; ++i) {
      int rA = row0 + wid * 32 + i * 16 + srow;
      rA = rA < M ? rA : M - 1;                      // clamp for ragged M
      const _Float16* gA = A + (size_t)rA * K + kt + scol;
      _Float16* lA = As + (wid * 32 + i * 16) * BK;  // wave-uniform base; HW adds lane*16B
      __builtin_amdgcn_global_load_lds(
          (const __attribute__((address_space(1))) void*)gA,
          (__attribute__((address_space(3))) void*)lA, 16, 0, 0);
      int rB = col0 + wid * 32 + i * 16 + srow;      // N=512, exact
      const _Float16* gB = B + (size_t)rB * K + kt + scol;
      _Float16* lB = Bs + (wid * 32 + i * 16) * BK;
      __builtin_amdgcn_global_load_lds(
          (const __attribute__((address_space(1))) void*)gB,
          (__attribute__((address_space(3))) void*)lB, 16, 0, 0);
    }
    __syncthreads();

    const int fr = lane & 15;
    const int kg = (lane >> 4) * 8;
    f16x8 af[4], bfr[4];
#pragma unroll
    for (int mi = 0; mi < 4; ++mi)
      af[mi] = *reinterpret_cast<const f16x8*>(As + (wm * 64 + mi * 16 + fr) * BK + kg);
#pragma unroll
    for (int ni = 0; ni < 4; ++ni)
      bfr[ni] = *reinterpret_cast<const f16x8*>(Bs + (wn * 64 + ni * 16 + fr) * BK + kg);
#pragma unroll
    for (int mi = 0; mi < 4; ++mi)
#pragma unroll
      for (int ni = 0; ni < 4; ++ni)
        acc[mi][ni] = __builtin_amdgcn_mfma_f32_16x16x32_f16(af[mi], bfr[ni], acc[mi][ni], 0, 0, 0);
    __syncthreads();
  }

  // epilogue: C/D layout col=lane&15, row=(lane>>4)*4+j
  const int crow = (lane >> 4) * 4;
  const int ccol = lane & 15;
#pragma unroll
  for (int ni = 0; ni < 4; ++ni) {
    const int gc = col0 + wn * 64 + ni * 16 + ccol;
    const float bv = has_bias ? bias[gc] : 0.0f;
#pragma unroll
    for (int mi = 0; mi < 4; ++mi) {
#pragma unroll
      for (int j = 0; j < 4; ++j) {
        const int gr = row0 + wm * 64 + mi * 16 + crow + j;
        if (gr < M) C[(size_t)gr * N + gc] = (_Float16)(acc[mi][ni][j] + bv);
      }
    }
  }
}

// ---------------- edge kernel: out[e] = W2 . relu(Hd[row[e]] + Hr[col[e]]) + b2 ----------------
// 4 edges per wave: 16-lane group g handles edge e0+g; lane li covers cols li*8 + 128k.
__global__ __launch_bounds__(256) void edge_kernel(
    const _Float16* __restrict__ Hd,
    const _Float16* __restrict__ Hr,
    const int* __restrict__ row,
    const int* __restrict__ col,
    const float* __restrict__ W2,
    const float* __restrict__ b2,
    float* __restrict__ out)
{
  const int lane = threadIdx.x & 63;
  const int li = lane & 15;
  const int g  = lane >> 4;
  const int wave = (blockIdx.x * blockDim.x + threadIdx.x) >> 6;
  const int nwaves = (gridDim.x * blockDim.x) >> 6;

  // W2 fragment (same for all 4 groups): lane covers elems li*8 + 128k, k=0..3
  f16x8 w2v[4];
#pragma unroll
  for (int k = 0; k < 4; ++k) {
    const float* p = W2 + li * 8 + k * 128;
    f16x8 q;
#pragma unroll
    for (int j = 0; j < 8; ++j) q[j] = (_Float16)p[j];
    w2v[k] = q;
  }
  const float bias2 = *b2;
  const f16x8 zero8 = (f16x8)(_Float16)0;

  for (int e0 = wave * 4; e0 < NEDGE; e0 += nwaves * 4) {
    const int e = e0 + g;                 // NEDGE % 4 == 0
    const int r = row[e];
    const int c = col[e];
    const _Float16* hd = Hd + (size_t)r * HIDDEN;
    const _Float16* hr = Hr + (size_t)c * HIDDEN;
    float acc = 0.f;
#pragma unroll
    for (int k = 0; k < 4; ++k) {
      const int o = li * 8 + k * 128;
      f16x8 vd = *reinterpret_cast<const f16x8*>(hd + o);
      f16x8 vr = *reinterpret_cast<const f16x8*>(hr + o);
      f16x8 s = vd + vr;                               // v_pk_add_f16 x4
      s = __builtin_elementwise_max(s, zero8);         // v_pk_max_f16 x4
#if defined(HAVE_FDOT2)
#pragma unroll
      for (int j = 0; j < 4; ++j) {
        f16x2 sp = {s[2 * j], s[2 * j + 1]};
        f16x2 wp = {w2v[k][2 * j], w2v[k][2 * j + 1]};
        acc = __builtin_amdgcn_fdot2(sp, wp, acc, false);  // v_dot2_f32_f16
      }
#else
#pragma unroll
      for (int j = 0; j < 8; ++j)
        acc += (float)s[j] * (float)w2v[k][j];
#endif
    }
    // reduce within the 16-lane group (handles all 4 edges at once)
#pragma unroll
    for (int off = 8; off >= 1; off >>= 1)
      acc += __shfl_xor(acc, off);
    if (li == 0) out[e] = acc + bias2;
  }
}

extern "C" void kernel_launch(void* const* d_in, const int* in_sizes, int n_in,
                              void* d_out, int out_size, void* d_ws, size_t ws_size,
                              hipStream_t stream) {
  const float* z_drug  = (const float*)d_in[0];
  const float* z_react = (const float*)d_in[1];
  const int*   row     = (const int*)d_in[2];
  const int*   col     = (const int*)d_in[3];
  const float* W1      = (const float*)d_in[4];
  const float* b1      = (const float*)d_in[5];
  const float* W2      = (const float*)d_in[6];
  const float* b2      = (const float*)d_in[7];
  float* out = (float*)d_out;

  char* ws = (char*)d_ws;
  size_t off = 0;
  auto alloc = [&](size_t bytes) {
    void* p = ws + off;
    off += (bytes + 255) & ~(size_t)255;
    return p;
  };
  _Float16* zd_f = (_Float16*)alloc((size_t)NDRUG * HIDDEN * 2);
  _Float16* zr_f = (_Float16*)alloc((size_t)NREACT * HIDDEN * 2);
  _Float16* wl_f = (_Float16*)alloc((size_t)HIDDEN * HIDDEN * 2);
  _Float16* wr_f = (_Float16*)alloc((size_t)HIDDEN * HIDDEN * 2);
  _Float16* Hd   = (_Float16*)alloc((size_t)NDRUG * HIDDEN * 2);
  _Float16* Hr   = (_Float16*)alloc((size_t)NREACT * HIDDEN * 2);

  cast_kernel<<<512, 256, 0, stream>>>(z_drug, zd_f, NDRUG * HIDDEN / 4);
  cast_kernel<<<2048, 256, 0, stream>>>(z_react, zr_f, NREACT * HIDDEN / 4);
  splitw1<<<512, 256, 0, stream>>>(W1, wl_f, wr_f);

  dim3 ggrid((NREACT + BM - 1) / BM, HIDDEN / BN, 2);  // (79, 4, 2)
  gemm_bt<<<ggrid, 256, 0, stream>>>(zd_f, zr_f, wl_f, wr_f, b1, Hd, Hr);

  edge_kernel<<<2048, 256, 0, stream>>>(Hd, Hr, row, col, W2, b2, out);
}